// Round 15
// baseline (210.181 us; speedup 1.0000x reference)
//
#include <hip/hip_runtime.h>

typedef __bf16 bf16x8 __attribute__((ext_vector_type(8)));
typedef float f32x4 __attribute__((ext_vector_type(4)));
typedef unsigned short u16;
typedef unsigned long long u64;

static constexpr int D = 256;      // feature dim
static constexpr int BROWS = 2048; // batch per view
static constexpr int QN = 65536;   // queue rows

__device__ __forceinline__ f32x4 mfma16(bf16x8 a, bf16x8 b, f32x4 c) {
  return __builtin_amdgcn_mfma_f32_16x16x32_bf16(a, b, c, 0, 0, 0);
}
__device__ __forceinline__ u16 bfb(float f) { return __builtin_bit_cast(u16, (__bf16)f); }

// ---- LDS staging, [ROWS][256] bf16 row-major, XOR swizzle ((row&7)<<4) ----
template<int ROWS>
__device__ __forceinline__ void stage_bf16(const u16* __restrict__ src, u16* lds, int tid) {
#pragma unroll
  for (int i = 0; i < ROWS / 8; ++i) {
    int slot = i * 256 + tid;
    int row = slot >> 5, s = slot & 31;
    bf16x8 d = *reinterpret_cast<const bf16x8*>(src + (size_t)row * D + s * 8);
    int byt = (row * 512 + s * 16) ^ ((row & 7) << 4);
    *reinterpret_cast<bf16x8*>(reinterpret_cast<char*>(lds) + byt) = d;
  }
}

template<int ROWS>
__device__ __forceinline__ void stage_f32(const float* __restrict__ src, u16* lds, int tid) {
#pragma unroll
  for (int i = 0; i < ROWS / 8; ++i) {
    int slot = i * 256 + tid;
    int row = slot >> 5, s = slot & 31;
    const float* p = src + (size_t)row * D + s * 8;
    float4 q0 = *reinterpret_cast<const float4*>(p);
    float4 q1 = *reinterpret_cast<const float4*>(p + 4);
    bf16x8 h;
    h[0] = (__bf16)q0.x; h[1] = (__bf16)q0.y; h[2] = (__bf16)q0.z; h[3] = (__bf16)q0.w;
    h[4] = (__bf16)q1.x; h[5] = (__bf16)q1.y; h[6] = (__bf16)q1.z; h[7] = (__bf16)q1.w;
    int byt = (row * 512 + s * 16) ^ ((row & 7) << 4);
    *reinterpret_cast<bf16x8*>(reinterpret_cast<char*>(lds) + byt) = h;
  }
}

__device__ __forceinline__ bf16x8 fragld(const u16* lds, int row, int ks, int lane) {
  int byt = (row * 512 + ((ks * 64 + ((lane >> 4) << 4)) ^ ((row & 7) << 4)));
  return *reinterpret_cast<const bf16x8*>(reinterpret_cast<const char*>(lds) + byt);
}

// ---- 1. transpose+convert W [k][n] f32 -> Wt [n][k] bf16 ----
__global__ void wt_convert(const float* __restrict__ W1, const float* __restrict__ W2,
                           u16* __restrict__ Wt) {
  const float* W = blockIdx.x == 0 ? W1 : W2;
  u16* o = Wt + blockIdx.x * 65536;
  int n = threadIdx.x;
  int k0 = blockIdx.y * 32;
#pragma unroll
  for (int jj = 0; jj < 4; ++jj) {
    bf16x8 h;
#pragma unroll
    for (int j = 0; j < 8; ++j) h[j] = (__bf16)W[(size_t)(k0 + jj * 8 + j) * 256 + n];
    *reinterpret_cast<bf16x8*>(o + n * 256 + k0 + jj * 8) = h;
  }
}

// ---- 2. projection layer GEMM: out = act(A @ W + b), M-tile 64, N-tile 128 ----
template<bool SRC_F32, bool RELU>
__global__ __launch_bounds__(256) void proj_kernel(
    const float* __restrict__ h1, const float* __restrict__ h2,
    const u16* __restrict__ Asrc, const u16* __restrict__ Wt,
    const float* __restrict__ bias, u16* __restrict__ out_bf,
    float* __restrict__ out_f32) {
  __shared__ u16 Alds[64 * 256];
  __shared__ u16 Blds[128 * 256];
  int tid = threadIdx.x;
  int r0 = blockIdx.y * 64, n0 = blockIdx.x * 128;
  if constexpr (SRC_F32) {
    const float* src = (r0 < BROWS) ? (h1 + (size_t)r0 * D) : (h2 + (size_t)(r0 - BROWS) * D);
    stage_f32<64>(src, Alds, tid);
  } else {
    stage_bf16<64>(Asrc + (size_t)r0 * D, Alds, tid);
  }
  stage_bf16<128>(Wt + (size_t)n0 * D, Blds, tid);
  __syncthreads();

  int lane = tid & 63, w = tid >> 6, wm = w >> 1, wn = w & 1;
  f32x4 acc[2][4];
  const f32x4 vz = {0.f, 0.f, 0.f, 0.f};
#pragma unroll
  for (int m = 0; m < 2; ++m)
#pragma unroll
    for (int n = 0; n < 4; ++n) acc[m][n] = vz;

#pragma unroll
  for (int ks = 0; ks < 8; ++ks) {
    bf16x8 a[2], b[4];
#pragma unroll
    for (int i = 0; i < 2; ++i) a[i] = fragld(Alds, wm * 32 + i * 16 + (lane & 15), ks, lane);
#pragma unroll
    for (int i = 0; i < 4; ++i) b[i] = fragld(Blds, wn * 64 + i * 16 + (lane & 15), ks, lane);
#pragma unroll
    for (int m = 0; m < 2; ++m)
#pragma unroll
      for (int n = 0; n < 4; ++n) acc[m][n] = mfma16(a[m], b[n], acc[m][n]);
  }

#pragma unroll
  for (int m = 0; m < 2; ++m)
#pragma unroll
    for (int n = 0; n < 4; ++n)
#pragma unroll
      for (int j = 0; j < 4; ++j) {
        int row = r0 + wm * 32 + m * 16 + ((lane >> 4) << 2) + j;
        int col = n0 + wn * 64 + n * 16 + (lane & 15);
        float v = acc[m][n][j] + bias[col];
        if constexpr (RELU) {
          v = fmaxf(v, 0.f);
          out_bf[(size_t)row * D + col] = bfb(v);
        } else {
          out_f32[(size_t)row * D + col] = v;
        }
      }
}

// ---- 3. row L2-normalize: Z f32 -> ZNb bf16 (all rows); rows<2048 also f32 to d_out ----
__global__ void normalize_k(const float* __restrict__ Z, u16* __restrict__ ZNb,
                            float* __restrict__ outq) {
  int row = blockIdx.x * 4 + (threadIdx.x >> 6);
  int lane = threadIdx.x & 63;
  float4 v = *reinterpret_cast<const float4*>(Z + (size_t)row * D + lane * 4);
  float ss = v.x * v.x + v.y * v.y + v.z * v.z + v.w * v.w;
#pragma unroll
  for (int m = 1; m <= 32; m <<= 1) ss += __shfl_xor(ss, m, 64);
  float s = 1.f / fmaxf(sqrtf(ss), 1e-12f);
  float ox = v.x * s, oy = v.y * s, oz = v.z * s, ow = v.w * s;
  u64 pk = (u64)bfb(ox) | ((u64)bfb(oy) << 16) | ((u64)bfb(oz) << 32) | ((u64)bfb(ow) << 48);
  *reinterpret_cast<u64*>(ZNb + (size_t)row * D + lane * 4) = pk;
  if (row < BROWS) {
    float* p = outq + (size_t)row * D + lane * 4;
    p[0] = ox; p[1] = oy; p[2] = oz; p[3] = ow;
  }
}

// ---- 4. NN search: barrier-free wave-private design ----
// block = ONE wave (64 threads) owning 64 queue cols (bq 128 VGPR) and a
// PRIVATE 16KB LDS (2 x 8KB bufs, 16-row chunks). grid (1024, 2) = 2048
// blocks -> 8 independent waves/CU (LDS 128KB, regs ~180 <= 256 via
// launch_bounds(64,2)). Zero s_barrier: the r10 lockstep serialized
// MFMA/VALU/DS phases across all 8 waves (r14 analysis: pipe demands SUM
// to the wall); decoupled waves let the CU overlap them. Sync is the
// wave's own vmcnt: stage for chunk i+1 is issued AFTER the mfmas that
// consumed buf[(i+1)&1]'s previous contents (in-order wave => those
// ds_reads drained), wait is vmcnt(1) (store may remain outstanding).
__global__ __launch_bounds__(64, 2) void nn_gemm(const float* __restrict__ queue,
                                                 const u16* __restrict__ ZNb,
                                                 unsigned* __restrict__ nkey) {
  __shared__ char Abuf[2][8192];
  const int lane = threadIdx.x;
  const int bx = blockIdx.x, by = blockIdx.y;
  const int colbase = bx * 64;
  const int hi16 = (lane >> 4) << 4;

  // this wave's 64 queue cols -> 32 bf16x8 frags (verbatim r10 layout)
  bf16x8 b[4][8];
#pragma unroll
  for (int cf = 0; cf < 4; ++cf)
#pragma unroll
    for (int ks = 0; ks < 8; ++ks) {
      const float* p = queue + (size_t)(colbase + cf * 16 + (lane & 15)) * D + ks * 32 + ((lane >> 4) << 3);
      float4 q0 = *reinterpret_cast<const float4*>(p);
      float4 q1 = *reinterpret_cast<const float4*>(p + 4);
      bf16x8 h;
      h[0] = (__bf16)q0.x; h[1] = (__bf16)q0.y; h[2] = (__bf16)q0.z; h[3] = (__bf16)q0.w;
      h[4] = (__bf16)q1.x; h[5] = (__bf16)q1.y; h[6] = (__bf16)q1.z; h[7] = (__bf16)q1.w;
      b[cf][ks] = h;
    }

  // 16-row chunk staging: 8 x 1KB loads; inverse 3-bit swizzle on source.
  // load c covers rows 2c + (lane>>5); dest linear = c*1024 + lane*16.
  int goff[8];
#pragma unroll
  for (int c = 0; c < 8; ++c) {
    int r = c * 2 + (lane >> 5);
    int s = lane & 31;
    goff[c] = r * 512 + ((s ^ (r & 7)) << 4);
  }

  const char* gbase = (const char*)ZNb + (size_t)(by * 2048) * 512;  // 2048 rows/half

  // prologue: stage chunk 0 -> buf0
#pragma unroll
  for (int c = 0; c < 8; ++c)
    __builtin_amdgcn_global_load_lds((const unsigned*)(gbase + goff[c]),
                                     (unsigned*)(Abuf[0] + c * 1024), 16, 0, 0);

  const unsigned idbase = (unsigned)((lane >> 4) << 2);
  const int sw = (lane & 7) << 4;
  for (int i = 0; i < 128; ++i) {
    if (i == 0) {
      asm volatile("s_waitcnt vmcnt(0)" ::: "memory");
    } else {
      asm volatile("s_waitcnt vmcnt(1)" ::: "memory");
    }
    __builtin_amdgcn_sched_barrier(0);

    f32x4 acc[4];
    const f32x4 vinit = {4.f, 4.f, 4.f, 4.f};
#pragma unroll
    for (int cf = 0; cf < 4; ++cf) acc[cf] = vinit;

    const char* buf = Abuf[i & 1];
    const char* pe = buf + (lane & 15) * 512 + (hi16 ^ sw);
    const char* po = buf + (lane & 15) * 512 + ((64 + hi16) ^ sw);
    __builtin_amdgcn_s_setprio(1);
#pragma unroll
    for (int k2 = 0; k2 < 4; ++k2) {
      bf16x8 a_e = *reinterpret_cast<const bf16x8*>(pe + k2 * 128);
      bf16x8 a_o = *reinterpret_cast<const bf16x8*>(po + k2 * 128);
#pragma unroll
      for (int cf = 0; cf < 4; ++cf) acc[cf] = mfma16(b[cf][2 * k2], a_e, acc[cf]);
#pragma unroll
      for (int cf = 0; cf < 4; ++cf) acc[cf] = mfma16(b[cf][2 * k2 + 1], a_o, acc[cf]);
    }
    __builtin_amdgcn_s_setprio(0);

    // issue stage for chunk (i+1)&127 into buf[(i+1)&1] AFTER its previous
    // contents were consumed above (iter-127 wrap restage is never read)
    {
      const char* g = gbase + (size_t)((i + 1) & 127) * 8192;
      char* dst = Abuf[(i + 1) & 1];
#pragma unroll
      for (int c = 0; c < 8; ++c)
        __builtin_amdgcn_global_load_lds((const unsigned*)(g + goff[c]),
                                         (unsigned*)(dst + c * 1024), 16, 0, 0);
    }

    // in-lane argmax over this wave's 64 cols for row (lane&15)
    unsigned kk;
    {
      unsigned m01, m23;
      {
        unsigned c0 = (__float_as_uint(acc[0][0]) & 0xFFFFFFC0u) | (idbase + 0);
        unsigned c1 = (__float_as_uint(acc[0][1]) & 0xFFFFFFC0u) | (idbase + 1);
        unsigned c2 = (__float_as_uint(acc[0][2]) & 0xFFFFFFC0u) | (idbase + 2);
        unsigned c3 = (__float_as_uint(acc[0][3]) & 0xFFFFFFC0u) | (idbase + 3);
        unsigned d0 = (__float_as_uint(acc[1][0]) & 0xFFFFFFC0u) | (idbase + 16);
        unsigned d1 = (__float_as_uint(acc[1][1]) & 0xFFFFFFC0u) | (idbase + 17);
        unsigned d2 = (__float_as_uint(acc[1][2]) & 0xFFFFFFC0u) | (idbase + 18);
        unsigned d3 = (__float_as_uint(acc[1][3]) & 0xFFFFFFC0u) | (idbase + 19);
        unsigned a = c0 > c1 ? c0 : c1, bb = c2 > c3 ? c2 : c3;
        unsigned c = d0 > d1 ? d0 : d1, d = d2 > d3 ? d2 : d3;
        a = a > bb ? a : bb; c = c > d ? c : d;
        m01 = a > c ? a : c;
      }
      {
        unsigned c0 = (__float_as_uint(acc[2][0]) & 0xFFFFFFC0u) | (idbase + 32);
        unsigned c1 = (__float_as_uint(acc[2][1]) & 0xFFFFFFC0u) | (idbase + 33);
        unsigned c2 = (__float_as_uint(acc[2][2]) & 0xFFFFFFC0u) | (idbase + 34);
        unsigned c3 = (__float_as_uint(acc[2][3]) & 0xFFFFFFC0u) | (idbase + 35);
        unsigned d0 = (__float_as_uint(acc[3][0]) & 0xFFFFFFC0u) | (idbase + 48);
        unsigned d1 = (__float_as_uint(acc[3][1]) & 0xFFFFFFC0u) | (idbase + 49);
        unsigned d2 = (__float_as_uint(acc[3][2]) & 0xFFFFFFC0u) | (idbase + 50);
        unsigned d3 = (__float_as_uint(acc[3][3]) & 0xFFFFFFC0u) | (idbase + 51);
        unsigned a = c0 > c1 ? c0 : c1, bb = c2 > c3 ? c2 : c3;
        unsigned c = d0 > d1 ? d0 : d1, d = d2 > d3 ? d2 : d3;
        a = a > bb ? a : bb; c = c > d ? c : d;
        m23 = a > c ? a : c;
      }
      unsigned k = m01 > m23 ? m01 : m23;
      unsigned o = (unsigned)__shfl_xor((int)k, 16, 64); if (o > k) k = o;
      o = (unsigned)__shfl_xor((int)k, 32, 64); if (o > k) k = o;
      kk = k;
    }
    if (lane < 16) {
      size_t row0 = (size_t)(by * 2048 + i * 16 + lane);
      nkey[row0 * 1024 + bx] = kk;
    }
  }
}

// ---- 5. reduce 1024 partials/row -> best col, gather neighbor row as bf16 ----
__global__ void nn_finish(const unsigned* __restrict__ nkey, const float* __restrict__ queue,
                          u16* __restrict__ NNb) {
  int row = blockIdx.x * 4 + (threadIdx.x >> 6);
  int lane = threadIdx.x & 63;
  const uint4* p = reinterpret_cast<const uint4*>(nkey + (size_t)row * 1024);
  uint4 q0 = p[lane], q1 = p[lane + 64], q2 = p[lane + 128], q3 = p[lane + 192];
  unsigned vs[16] = {q0.x, q0.y, q0.z, q0.w, q1.x, q1.y, q1.z, q1.w,
                     q2.x, q2.y, q2.z, q2.w, q3.x, q3.y, q3.z, q3.w};
  unsigned mx = 0;
#pragma unroll
  for (int t = 0; t < 16; ++t) mx = vs[t] > mx ? vs[t] : mx;
#pragma unroll
  for (int m = 1; m <= 32; m <<= 1) {
    unsigned o = (unsigned)__shfl_xor((int)mx, m, 64);
    if (o > mx) mx = o;
  }
  unsigned pos = 0xFFFFFFFFu;
#pragma unroll
  for (int t = 0; t < 16; ++t) {
    unsigned pp = (unsigned)((lane + (t >> 2) * 64) * 4 + (t & 3));
    if (vs[t] == mx && pp < pos) pos = pp;
  }
#pragma unroll
  for (int m = 1; m <= 32; m <<= 1) {
    unsigned o = (unsigned)__shfl_xor((int)pos, m, 64);
    if (o < pos) pos = o;
  }
  int idx = (int)(pos * 64 + (mx & 63u));
  float4 v = *(reinterpret_cast<const float4*>(queue + (size_t)idx * D) + lane);
  u64 pk = (u64)bfb(v.x) | ((u64)bfb(v.y) << 16) | ((u64)bfb(v.z) << 32) | ((u64)bfb(v.w) << 48);
  *reinterpret_cast<u64*>(NNb + (size_t)row * D + lane * 4) = pk;
}

// ---- 7. CE logits GEMM with fused softmax partials + diag + FIFO-copy tail ----
__global__ __launch_bounds__(256) void ce_gemm(const u16* __restrict__ NNb,
                                               const u16* __restrict__ ZNb,
                                               float2* __restrict__ rowpart,
                                               float2* __restrict__ colpart,
                                               float* __restrict__ diag,
                                               const float* __restrict__ cq,
                                               float* __restrict__ copydst) {
  __shared__ u16 Alds[128 * 256];
  __shared__ u16 Blds[128 * 256];
  int tid = threadIdx.x;
  int cb = blockIdx.x, rb = blockIdx.y, mat = blockIdx.z;
  const u16* A = NNb + (size_t)(mat * BROWS + rb * 128) * D;
  const u16* Bm = ZNb + (size_t)((mat == 0 ? BROWS : 0) + cb * 128) * D;
  stage_bf16<128>(A, Alds, tid);
  stage_bf16<128>(Bm, Blds, tid);
  __syncthreads();

  int lane = tid & 63, w = tid >> 6, wm = w >> 1, wn = w & 1;
  f32x4 acc[4][4];
  const f32x4 vz = {0.f, 0.f, 0.f, 0.f};
#pragma unroll
  for (int m = 0; m < 4; ++m)
#pragma unroll
    for (int n = 0; n < 4; ++n) acc[m][n] = vz;

#pragma unroll
  for (int ks = 0; ks < 8; ++ks) {
    bf16x8 a[4], b[4];
#pragma unroll
    for (int i = 0; i < 4; ++i) a[i] = fragld(Alds, wm * 64 + i * 16 + (lane & 15), ks, lane);
#pragma unroll
    for (int i = 0; i < 4; ++i) b[i] = fragld(Blds, wn * 64 + i * 16 + (lane & 15), ks, lane);
#pragma unroll
    for (int m = 0; m < 4; ++m)
#pragma unroll
      for (int n = 0; n < 4; ++n) acc[m][n] = mfma16(a[m], b[n], acc[m][n]);
  }

#pragma unroll
  for (int m = 0; m < 4; ++m)
#pragma unroll
    for (int n = 0; n < 4; ++n) acc[m][n] = acc[m][n] * 10.f;  // 1/TEMP

  int rbase = rb * 128 + wm * 64;
  int cbase = cb * 128 + wn * 64;

#pragma unroll
  for (int m = 0; m < 4; ++m)
#pragma unroll
    for (int j = 0; j < 4; ++j) {
      float mx = -3e38f;
#pragma unroll
      for (int n = 0; n < 4; ++n) mx = fmaxf(mx, acc[m][n][j]);
#pragma unroll
      for (int s = 1; s <= 8; s <<= 1) mx = fmaxf(mx, __shfl_xor(mx, s, 64));
      float sm = 0.f;
#pragma unroll
      for (int n = 0; n < 4; ++n) sm += __expf(acc[m][n][j] - mx);
#pragma unroll
      for (int s = 1; s <= 8; s <<= 1) sm += __shfl_xor(sm, s, 64);
      if ((lane & 15) == 0) {
        int r = rbase + m * 16 + ((lane >> 4) << 2) + j;
        rowpart[(((size_t)mat * BROWS + r) << 5) + cb * 2 + wn] = make_float2(mx, sm);
      }
    }

#pragma unroll
  for (int n = 0; n < 4; ++n) {
    float mx = -3e38f;
#pragma unroll
    for (int m = 0; m < 4; ++m)
#pragma unroll
      for (int j = 0; j < 4; ++j) mx = fmaxf(mx, acc[m][n][j]);
#pragma unroll
    for (int s = 16; s <= 32; s <<= 1) mx = fmaxf(mx, __shfl_xor(mx, s, 64));
    float sm = 0.f;
#pragma unroll
    for (int m = 0; m < 4; ++m)
#pragma unroll
      for (int j = 0; j < 4; ++j) sm += __expf(acc[m][n][j] - mx);
#pragma unroll
    for (int s = 16; s <= 32; s <<= 1) sm += __shfl_xor(sm, s, 64);
    if (lane < 16) {
      int c = cbase + n * 16 + lane;
      colpart[(((size_t)mat * BROWS + c) << 5) + rb * 2 + wm] = make_float2(mx, sm);
    }
  }

#pragma unroll
  for (int m = 0; m < 4; ++m)
#pragma unroll
    for (int n = 0; n < 4; ++n)
#pragma unroll
      for (int j = 0; j < 4; ++j) {
        int rg = rbase + m * 16 + ((lane >> 4) << 2) + j;
        int cg = cbase + n * 16 + (lane & 15);
        if (rg == cg) diag[mat * BROWS + rg] = acc[m][n][j];
      }

  // FIFO copy slice: block id 0..511, 31 float4 per thread (exact cover)
  {
    int cbid = cb + rb * 16 + mat * 256;
    const float4* src = reinterpret_cast<const float4*>(cq);
    float4* dst = reinterpret_cast<float4*>(copydst);
    size_t base = (size_t)cbid * 7936 + (size_t)tid;
#pragma unroll 4
    for (int k = 0; k < 31; ++k) dst[base + (size_t)k * 256] = src[base + (size_t)k * 256];
  }
}

// ---- 8a. per-64-row loss partials (64 blocks) ----
__global__ void loss_part(const float2* __restrict__ rowpart, const float2* __restrict__ colpart,
                          const float* __restrict__ diag, float* __restrict__ lpart) {
  __shared__ float red[256];
  int tid = threadIdx.x;
  int r = blockIdx.x * 64 + (tid >> 2), q = tid & 3;
  const float2* rp = rowpart + ((size_t)r << 5) + q * 8;
  float2 e[8];
#pragma unroll
  for (int i = 0; i < 8; ++i) e[i] = rp[i];
  float mx = e[0].x;
#pragma unroll
  for (int i = 1; i < 8; ++i) mx = fmaxf(mx, e[i].x);
  mx = fmaxf(mx, __shfl_xor(mx, 1, 64));
  mx = fmaxf(mx, __shfl_xor(mx, 2, 64));
  float s = 0.f;
#pragma unroll
  for (int i = 0; i < 8; ++i) s += e[i].y * __expf(e[i].x - mx);
  s += __shfl_xor(s, 1, 64);
  s += __shfl_xor(s, 2, 64);
  float rlse = mx + __logf(s);

  const float2* cp = colpart + ((size_t)r << 5) + q * 8;
#pragma unroll
  for (int i = 0; i < 8; ++i) e[i] = cp[i];
  float mx2 = e[0].x;
#pragma unroll
  for (int i = 1; i < 8; ++i) mx2 = fmaxf(mx2, e[i].x);
  mx2 = fmaxf(mx2, __shfl_xor(mx2, 1, 64));
  mx2 = fmaxf(mx2, __shfl_xor(mx2, 2, 64));
  float s2 = 0.f;
#pragma unroll
  for (int i = 0; i < 8; ++i) s2 += e[i].y * __expf(e[i].x - mx2);
  s2 += __shfl_xor(s2, 1, 64);
  s2 += __shfl_xor(s2, 2, 64);
  float clse = mx2 + __logf(s2);

  red[tid] = (q == 0) ? (rlse + clse - 2.f * diag[r]) : 0.f;
  __syncthreads();
  for (int st = 128; st > 0; st >>= 1) {
    if (tid < st) red[tid] += red[tid + st];
    __syncthreads();
  }
  if (tid == 0) lpart[blockIdx.x] = red[0];
}

// ---- 8b. final scalar ----
__global__ void loss_final(const float* __restrict__ lpart, float* __restrict__ out) {
  int lane = threadIdx.x;
  float v = lpart[lane];
#pragma unroll
  for (int m = 1; m <= 32; m <<= 1) v += __shfl_xor(v, m, 64);
  if (lane == 0) out[0] = v * (1.f / 8192.f);
}

extern "C" void kernel_launch(void* const* d_in, const int* in_sizes, int n_in,
                              void* d_out, int out_size, void* d_ws, size_t ws_size,
                              hipStream_t stream) {
  const float* h1 = (const float*)d_in[0];
  const float* h2 = (const float*)d_in[1];
  const float* W1 = (const float*)d_in[2];
  const float* b1 = (const float*)d_in[3];
  const float* W2 = (const float*)d_in[4];
  const float* b2 = (const float*)d_in[5];
  const float* fq = (const float*)d_in[6];
  float* out = (float*)d_out;

  char* ws = (char*)d_ws;
  u16* Wt        = (u16*)(ws);                        // [2][256][256] bf16   (256 KB)
  u16* Ybf       = (u16*)(ws + 262144);               // [4096][256] bf16     (2 MB)
  float* Z       = (float*)(ws + 2359296);            // [4096][256] f32      (4 MB)
  u16* ZNb       = (u16*)(ws + 6553600);              // [4096][256] bf16     (2 MB)
  unsigned* nkey = (unsigned*)(ws + 8650752);         // [4096][1024] u32     (16 MB)
  u16* NNb       = (u16*)(ws + 25444352);             // [4096][256] bf16     (2 MB)
  float2* rowp   = (float2*)(ws + 27541504);          // [2][2048][32]        (1 MB)
  float2* colp   = (float2*)(ws + 28590080);          // [2][2048][32]        (1 MB)
  float* diag    = (float*)(ws + 29638656);           // [2][2048]
  float* lpart   = (float*)(ws + 29655040);           // [64]

  wt_convert<<<dim3(2, 8), dim3(256), 0, stream>>>(W1, W2, Wt);
  proj_kernel<true, true><<<dim3(2, 64), dim3(256), 0, stream>>>(
      h1, h2, (const u16*)nullptr, Wt, b1, Ybf, (float*)nullptr);
  proj_kernel<false, false><<<dim3(2, 64), dim3(256), 0, stream>>>(
      (const float*)nullptr, (const float*)nullptr, Ybf, Wt + 65536, b2, (u16*)nullptr, Z);
  normalize_k<<<dim3(1024), dim3(256), 0, stream>>>(Z, ZNb, out + 1);
  nn_gemm<<<dim3(1024, 2), dim3(64), 0, stream>>>(fq, ZNb, nkey);
  nn_finish<<<dim3(1024), dim3(256), 0, stream>>>(nkey, fq, NNb);
  ce_gemm<<<dim3(16, 16, 2), dim3(256), 0, stream>>>(NNb, ZNb, rowp, colp, diag,
                                                     fq, out + 1 + (size_t)BROWS * D);
  loss_part<<<dim3(64), dim3(256), 0, stream>>>(rowp, colp, diag, lpart);
  loss_final<<<dim3(1), dim3(64), 0, stream>>>(lpart, out);
}

// Round 16
// 180.274 us; speedup vs baseline: 1.1659x; 1.1659x over previous
//
#include <hip/hip_runtime.h>

typedef __bf16 bf16x8 __attribute__((ext_vector_type(8)));
typedef float f32x4 __attribute__((ext_vector_type(4)));
typedef unsigned short u16;
typedef unsigned long long u64;

static constexpr int D = 256;      // feature dim
static constexpr int BROWS = 2048; // batch per view
static constexpr int QN = 65536;   // queue rows

__device__ __forceinline__ f32x4 mfma16(bf16x8 a, bf16x8 b, f32x4 c) {
  return __builtin_amdgcn_mfma_f32_16x16x32_bf16(a, b, c, 0, 0, 0);
}
__device__ __forceinline__ u16 bfb(float f) { return __builtin_bit_cast(u16, (__bf16)f); }

// ---- LDS staging, [ROWS][256] bf16 row-major, XOR swizzle ((row&7)<<4) ----
template<int ROWS>
__device__ __forceinline__ void stage_bf16(const u16* __restrict__ src, u16* lds, int tid) {
#pragma unroll
  for (int i = 0; i < ROWS / 8; ++i) {
    int slot = i * 256 + tid;
    int row = slot >> 5, s = slot & 31;
    bf16x8 d = *reinterpret_cast<const bf16x8*>(src + (size_t)row * D + s * 8);
    int byt = (row * 512 + s * 16) ^ ((row & 7) << 4);
    *reinterpret_cast<bf16x8*>(reinterpret_cast<char*>(lds) + byt) = d;
  }
}

template<int ROWS>
__device__ __forceinline__ void stage_f32(const float* __restrict__ src, u16* lds, int tid) {
#pragma unroll
  for (int i = 0; i < ROWS / 8; ++i) {
    int slot = i * 256 + tid;
    int row = slot >> 5, s = slot & 31;
    const float* p = src + (size_t)row * D + s * 8;
    float4 q0 = *reinterpret_cast<const float4*>(p);
    float4 q1 = *reinterpret_cast<const float4*>(p + 4);
    bf16x8 h;
    h[0] = (__bf16)q0.x; h[1] = (__bf16)q0.y; h[2] = (__bf16)q0.z; h[3] = (__bf16)q0.w;
    h[4] = (__bf16)q1.x; h[5] = (__bf16)q1.y; h[6] = (__bf16)q1.z; h[7] = (__bf16)q1.w;
    int byt = (row * 512 + s * 16) ^ ((row & 7) << 4);
    *reinterpret_cast<bf16x8*>(reinterpret_cast<char*>(lds) + byt) = h;
  }
}

__device__ __forceinline__ bf16x8 fragld(const u16* lds, int row, int ks, int lane) {
  int byt = (row * 512 + ((ks * 64 + ((lane >> 4) << 4)) ^ ((row & 7) << 4)));
  return *reinterpret_cast<const bf16x8*>(reinterpret_cast<const char*>(lds) + byt);
}

// ---- 1. transpose+convert W [k][n] f32 -> Wt [n][k] bf16 ----
// grid (2, 8): coalesced reads (fixed k, n across lanes), contiguous
// bf16x8 writes (thread owns n, 32 consecutive k's).
__global__ void wt_convert(const float* __restrict__ W1, const float* __restrict__ W2,
                           u16* __restrict__ Wt) {
  const float* W = blockIdx.x == 0 ? W1 : W2;
  u16* o = Wt + blockIdx.x * 65536;
  int n = threadIdx.x;
  int k0 = blockIdx.y * 32;
#pragma unroll
  for (int jj = 0; jj < 4; ++jj) {
    bf16x8 h;
#pragma unroll
    for (int j = 0; j < 8; ++j) h[j] = (__bf16)W[(size_t)(k0 + jj * 8 + j) * 256 + n];
    *reinterpret_cast<bf16x8*>(o + n * 256 + k0 + jj * 8) = h;
  }
}

// ---- 2. projection layer GEMM: out = act(A @ W + b), M-tile 64, N-tile 128 ----
// grid (2, 64) = 128 blocks. 4 waves: wm=w>>1 (2x32 rows), wn=w&1 (2x64 cols).
template<bool SRC_F32, bool RELU>
__global__ __launch_bounds__(256) void proj_kernel(
    const float* __restrict__ h1, const float* __restrict__ h2,
    const u16* __restrict__ Asrc, const u16* __restrict__ Wt,
    const float* __restrict__ bias, u16* __restrict__ out_bf,
    float* __restrict__ out_f32) {
  __shared__ u16 Alds[64 * 256];
  __shared__ u16 Blds[128 * 256];
  int tid = threadIdx.x;
  int r0 = blockIdx.y * 64, n0 = blockIdx.x * 128;
  if constexpr (SRC_F32) {
    const float* src = (r0 < BROWS) ? (h1 + (size_t)r0 * D) : (h2 + (size_t)(r0 - BROWS) * D);
    stage_f32<64>(src, Alds, tid);
  } else {
    stage_bf16<64>(Asrc + (size_t)r0 * D, Alds, tid);
  }
  stage_bf16<128>(Wt + (size_t)n0 * D, Blds, tid);
  __syncthreads();

  int lane = tid & 63, w = tid >> 6, wm = w >> 1, wn = w & 1;
  f32x4 acc[2][4];
  const f32x4 vz = {0.f, 0.f, 0.f, 0.f};
#pragma unroll
  for (int m = 0; m < 2; ++m)
#pragma unroll
    for (int n = 0; n < 4; ++n) acc[m][n] = vz;

#pragma unroll
  for (int ks = 0; ks < 8; ++ks) {
    bf16x8 a[2], b[4];
#pragma unroll
    for (int i = 0; i < 2; ++i) a[i] = fragld(Alds, wm * 32 + i * 16 + (lane & 15), ks, lane);
#pragma unroll
    for (int i = 0; i < 4; ++i) b[i] = fragld(Blds, wn * 64 + i * 16 + (lane & 15), ks, lane);
#pragma unroll
    for (int m = 0; m < 2; ++m)
#pragma unroll
      for (int n = 0; n < 4; ++n) acc[m][n] = mfma16(a[m], b[n], acc[m][n]);
  }

#pragma unroll
  for (int m = 0; m < 2; ++m)
#pragma unroll
    for (int n = 0; n < 4; ++n)
#pragma unroll
      for (int j = 0; j < 4; ++j) {
        int row = r0 + wm * 32 + m * 16 + ((lane >> 4) << 2) + j;
        int col = n0 + wn * 64 + n * 16 + (lane & 15);
        float v = acc[m][n][j] + bias[col];
        if constexpr (RELU) {
          v = fmaxf(v, 0.f);
          out_bf[(size_t)row * D + col] = bfb(v);
        } else {
          out_f32[(size_t)row * D + col] = v;
        }
      }
}

// ---- 3. row L2-normalize: Z f32 -> ZNb bf16 (all rows); rows<2048 also f32 to d_out ----
__global__ void normalize_k(const float* __restrict__ Z, u16* __restrict__ ZNb,
                            float* __restrict__ outq) {
  int row = blockIdx.x * 4 + (threadIdx.x >> 6);
  int lane = threadIdx.x & 63;
  float4 v = *reinterpret_cast<const float4*>(Z + (size_t)row * D + lane * 4);
  float ss = v.x * v.x + v.y * v.y + v.z * v.z + v.w * v.w;
#pragma unroll
  for (int m = 1; m <= 32; m <<= 1) ss += __shfl_xor(ss, m, 64);
  float s = 1.f / fmaxf(sqrtf(ss), 1e-12f);
  float ox = v.x * s, oy = v.y * s, oz = v.z * s, ow = v.w * s;
  u64 pk = (u64)bfb(ox) | ((u64)bfb(oy) << 16) | ((u64)bfb(oz) << 32) | ((u64)bfb(ow) << 48);
  *reinterpret_cast<u64*>(ZNb + (size_t)row * D + lane * 4) = pk;
  if (row < BROWS) {
    float* p = outq + (size_t)row * D + lane * 4;
    p[0] = ox; p[1] = oy; p[2] = oz; p[3] = ow;
  }
}

// ---- 4. NN search: r4-exact (fastest measured: 127us, MfmaUtil 47%) ----
// grid (256, 2). Swapped-operand 16x16 MFMA (row candidates in-lane).
// 3-buffer 2-deep prefetch, counted vmcnt (8/12), 2 barriers/chunk.
// NOTE (r11-r15): occupancy is register-pinned at 2 waves/SIMD (112 VGPR +
// 32 AGPR > 128 unified); fewer barriers, bigger chunks, M-splits, and
// wave-private decoupling all measured WORSE. This is the plateau config.
__global__ __launch_bounds__(256, 2) void nn_gemm(const float* __restrict__ queue,
                                                  const u16* __restrict__ ZNb,
                                                  unsigned* __restrict__ nkey) {
  __shared__ char Abuf[3][16384];
  const int tid = threadIdx.x, lane = tid & 63, w = tid >> 6;
  const int bx = blockIdx.x, by = blockIdx.y;
  const int colbase = bx * 256 + w * 64;
  const int hi16 = (lane >> 4) << 4;

  bf16x8 b[4][8];
#pragma unroll
  for (int cf = 0; cf < 4; ++cf)
#pragma unroll
    for (int ks = 0; ks < 8; ++ks) {
      const float* p = queue + (size_t)(colbase + cf * 16 + (lane & 15)) * D + ks * 32 + ((lane >> 4) << 3);
      float4 q0 = *reinterpret_cast<const float4*>(p);
      float4 q1 = *reinterpret_cast<const float4*>(p + 4);
      bf16x8 h;
      h[0] = (__bf16)q0.x; h[1] = (__bf16)q0.y; h[2] = (__bf16)q0.z; h[3] = (__bf16)q0.w;
      h[4] = (__bf16)q1.x; h[5] = (__bf16)q1.y; h[6] = (__bf16)q1.z; h[7] = (__bf16)q1.w;
      b[cf][ks] = h;
    }

  int goff[4];
#pragma unroll
  for (int c = 0; c < 4; ++c) {
    int r = w * 8 + c * 2 + (lane >> 5);
    int s = lane & 31;
    goff[c] = r * 512 + ((s ^ (r & 7)) << 4);
  }

  const char* gbase = (const char*)ZNb + (size_t)(by * 64) * 16384;

#pragma unroll
  for (int c = 0; c < 4; ++c)
    __builtin_amdgcn_global_load_lds((const unsigned*)(gbase + goff[c]),
                                     (unsigned*)(Abuf[0] + w * 4096 + c * 1024), 16, 0, 0);
#pragma unroll
  for (int c = 0; c < 4; ++c)
    __builtin_amdgcn_global_load_lds((const unsigned*)(gbase + 16384 + goff[c]),
                                     (unsigned*)(Abuf[1] + w * 4096 + c * 1024), 16, 0, 0);

  const unsigned idbase = (unsigned)((lane >> 4) << 2);
  const int sw = (lane & 7) << 4;
  int b0 = 0;
  for (int i = 0; i < 64; ++i) {
    {
      int nb = b0 + 2; if (nb >= 3) nb -= 3;
      const char* g = gbase + (size_t)((i + 2) & 63) * 16384;
      char* dst = Abuf[nb] + w * 4096;
#pragma unroll
      for (int c = 0; c < 4; ++c)
        __builtin_amdgcn_global_load_lds((const unsigned*)(g + goff[c]),
                                         (unsigned*)(dst + c * 1024), 16, 0, 0);
    }
    if (i < 2) {
      asm volatile("s_waitcnt vmcnt(8)" ::: "memory");
    } else {
      asm volatile("s_waitcnt vmcnt(12)" ::: "memory");
    }
    __builtin_amdgcn_s_barrier();
    __builtin_amdgcn_sched_barrier(0);

    f32x4 acc[4][2];
    const f32x4 vinit = {4.f, 4.f, 4.f, 4.f};
#pragma unroll
    for (int cf = 0; cf < 4; ++cf) {
      acc[cf][0] = vinit;
      acc[cf][1] = vinit;
    }

    const char* buf = Abuf[b0];
    const char* pe = buf + (lane & 15) * 512 + (hi16 ^ sw);
    const char* po = buf + (lane & 15) * 512 + ((64 + hi16) ^ sw);
    __builtin_amdgcn_s_setprio(1);
#pragma unroll
    for (int k2 = 0; k2 < 4; ++k2) {
      bf16x8 a0e = *reinterpret_cast<const bf16x8*>(pe + k2 * 128);
      bf16x8 a1e = *reinterpret_cast<const bf16x8*>(pe + k2 * 128 + 8192);
      bf16x8 a0o = *reinterpret_cast<const bf16x8*>(po + k2 * 128);
      bf16x8 a1o = *reinterpret_cast<const bf16x8*>(po + k2 * 128 + 8192);
#pragma unroll
      for (int cf = 0; cf < 4; ++cf) {
        acc[cf][0] = mfma16(b[cf][2 * k2], a0e, acc[cf][0]);
        acc[cf][1] = mfma16(b[cf][2 * k2], a1e, acc[cf][1]);
      }
#pragma unroll
      for (int cf = 0; cf < 4; ++cf) {
        acc[cf][0] = mfma16(b[cf][2 * k2 + 1], a0o, acc[cf][0]);
        acc[cf][1] = mfma16(b[cf][2 * k2 + 1], a1o, acc[cf][1]);
      }
    }
    __builtin_amdgcn_s_setprio(0);

    const int chunk = by * 64 + i;
    unsigned kk[2];
#pragma unroll
    for (int af = 0; af < 2; ++af) {
      unsigned m01, m23;
      {
        unsigned c0 = (__float_as_uint(acc[0][af][0]) & 0xFFFFFFC0u) | (idbase + 0);
        unsigned c1 = (__float_as_uint(acc[0][af][1]) & 0xFFFFFFC0u) | (idbase + 1);
        unsigned c2 = (__float_as_uint(acc[0][af][2]) & 0xFFFFFFC0u) | (idbase + 2);
        unsigned c3 = (__float_as_uint(acc[0][af][3]) & 0xFFFFFFC0u) | (idbase + 3);
        unsigned d0 = (__float_as_uint(acc[1][af][0]) & 0xFFFFFFC0u) | (idbase + 16);
        unsigned d1 = (__float_as_uint(acc[1][af][1]) & 0xFFFFFFC0u) | (idbase + 17);
        unsigned d2 = (__float_as_uint(acc[1][af][2]) & 0xFFFFFFC0u) | (idbase + 18);
        unsigned d3 = (__float_as_uint(acc[1][af][3]) & 0xFFFFFFC0u) | (idbase + 19);
        unsigned a = c0 > c1 ? c0 : c1, bb = c2 > c3 ? c2 : c3;
        unsigned c = d0 > d1 ? d0 : d1, d = d2 > d3 ? d2 : d3;
        a = a > bb ? a : bb; c = c > d ? c : d;
        m01 = a > c ? a : c;
      }
      {
        unsigned c0 = (__float_as_uint(acc[2][af][0]) & 0xFFFFFFC0u) | (idbase + 32);
        unsigned c1 = (__float_as_uint(acc[2][af][1]) & 0xFFFFFFC0u) | (idbase + 33);
        unsigned c2 = (__float_as_uint(acc[2][af][2]) & 0xFFFFFFC0u) | (idbase + 34);
        unsigned c3 = (__float_as_uint(acc[2][af][3]) & 0xFFFFFFC0u) | (idbase + 35);
        unsigned d0 = (__float_as_uint(acc[3][af][0]) & 0xFFFFFFC0u) | (idbase + 48);
        unsigned d1 = (__float_as_uint(acc[3][af][1]) & 0xFFFFFFC0u) | (idbase + 49);
        unsigned d2 = (__float_as_uint(acc[3][af][2]) & 0xFFFFFFC0u) | (idbase + 50);
        unsigned d3 = (__float_as_uint(acc[3][af][3]) & 0xFFFFFFC0u) | (idbase + 51);
        unsigned a = c0 > c1 ? c0 : c1, bb = c2 > c3 ? c2 : c3;
        unsigned c = d0 > d1 ? d0 : d1, d = d2 > d3 ? d2 : d3;
        a = a > bb ? a : bb; c = c > d ? c : d;
        m23 = a > c ? a : c;
      }
      unsigned k = m01 > m23 ? m01 : m23;
      unsigned o = (unsigned)__shfl_xor((int)k, 16, 64); if (o > k) k = o;
      o = (unsigned)__shfl_xor((int)k, 32, 64); if (o > k) k = o;
      kk[af] = k;
    }
    if (lane < 16) {
      size_t row0 = (size_t)(chunk * 32 + lane);
      nkey[row0 * 1024 + (bx << 2) + w] = kk[0];
      nkey[(row0 + 16) * 1024 + (bx << 2) + w] = kk[1];
    }

    __builtin_amdgcn_sched_barrier(0);
    __builtin_amdgcn_s_barrier();
    b0 = (b0 == 2) ? 0 : b0 + 1;
  }
}

// ---- 5. reduce 1024 partials/row -> best col, gather neighbor row as bf16 ----
__global__ void nn_finish(const unsigned* __restrict__ nkey, const float* __restrict__ queue,
                          u16* __restrict__ NNb) {
  int row = blockIdx.x * 4 + (threadIdx.x >> 6);
  int lane = threadIdx.x & 63;
  const uint4* p = reinterpret_cast<const uint4*>(nkey + (size_t)row * 1024);
  uint4 q0 = p[lane], q1 = p[lane + 64], q2 = p[lane + 128], q3 = p[lane + 192];
  unsigned vs[16] = {q0.x, q0.y, q0.z, q0.w, q1.x, q1.y, q1.z, q1.w,
                     q2.x, q2.y, q2.z, q2.w, q3.x, q3.y, q3.z, q3.w};
  unsigned mx = 0;
#pragma unroll
  for (int t = 0; t < 16; ++t) mx = vs[t] > mx ? vs[t] : mx;
#pragma unroll
  for (int m = 1; m <= 32; m <<= 1) {
    unsigned o = (unsigned)__shfl_xor((int)mx, m, 64);
    if (o > mx) mx = o;
  }
  unsigned pos = 0xFFFFFFFFu;
#pragma unroll
  for (int t = 0; t < 16; ++t) {
    unsigned pp = (unsigned)((lane + (t >> 2) * 64) * 4 + (t & 3));
    if (vs[t] == mx && pp < pos) pos = pp;
  }
#pragma unroll
  for (int m = 1; m <= 32; m <<= 1) {
    unsigned o = (unsigned)__shfl_xor((int)pos, m, 64);
    if (o < pos) pos = o;
  }
  int idx = (int)(pos * 64 + (mx & 63u));
  float4 v = *(reinterpret_cast<const float4*>(queue + (size_t)idx * D) + lane);
  u64 pk = (u64)bfb(v.x) | ((u64)bfb(v.y) << 16) | ((u64)bfb(v.z) << 32) | ((u64)bfb(v.w) << 48);
  *reinterpret_cast<u64*>(NNb + (size_t)row * D + lane * 4) = pk;
}

// ---- 7. CE logits GEMM with fused softmax partials + diag + FIFO-copy tail ----
__global__ __launch_bounds__(256) void ce_gemm(const u16* __restrict__ NNb,
                                               const u16* __restrict__ ZNb,
                                               float2* __restrict__ rowpart,
                                               float2* __restrict__ colpart,
                                               float* __restrict__ diag,
                                               const float* __restrict__ cq,
                                               float* __restrict__ copydst) {
  __shared__ u16 Alds[128 * 256];
  __shared__ u16 Blds[128 * 256];
  int tid = threadIdx.x;
  int cb = blockIdx.x, rb = blockIdx.y, mat = blockIdx.z;
  const u16* A = NNb + (size_t)(mat * BROWS + rb * 128) * D;
  const u16* Bm = ZNb + (size_t)((mat == 0 ? BROWS : 0) + cb * 128) * D;
  stage_bf16<128>(A, Alds, tid);
  stage_bf16<128>(Bm, Blds, tid);
  __syncthreads();

  int lane = tid & 63, w = tid >> 6, wm = w >> 1, wn = w & 1;
  f32x4 acc[4][4];
  const f32x4 vz = {0.f, 0.f, 0.f, 0.f};
#pragma unroll
  for (int m = 0; m < 4; ++m)
#pragma unroll
    for (int n = 0; n < 4; ++n) acc[m][n] = vz;

#pragma unroll
  for (int ks = 0; ks < 8; ++ks) {
    bf16x8 a[4], b[4];
#pragma unroll
    for (int i = 0; i < 4; ++i) a[i] = fragld(Alds, wm * 64 + i * 16 + (lane & 15), ks, lane);
#pragma unroll
    for (int i = 0; i < 4; ++i) b[i] = fragld(Blds, wn * 64 + i * 16 + (lane & 15), ks, lane);
#pragma unroll
    for (int m = 0; m < 4; ++m)
#pragma unroll
      for (int n = 0; n < 4; ++n) acc[m][n] = mfma16(a[m], b[n], acc[m][n]);
  }

#pragma unroll
  for (int m = 0; m < 4; ++m)
#pragma unroll
    for (int n = 0; n < 4; ++n) acc[m][n] = acc[m][n] * 10.f;  // 1/TEMP

  int rbase = rb * 128 + wm * 64;
  int cbase = cb * 128 + wn * 64;

#pragma unroll
  for (int m = 0; m < 4; ++m)
#pragma unroll
    for (int j = 0; j < 4; ++j) {
      float mx = -3e38f;
#pragma unroll
      for (int n = 0; n < 4; ++n) mx = fmaxf(mx, acc[m][n][j]);
#pragma unroll
      for (int s = 1; s <= 8; s <<= 1) mx = fmaxf(mx, __shfl_xor(mx, s, 64));
      float sm = 0.f;
#pragma unroll
      for (int n = 0; n < 4; ++n) sm += __expf(acc[m][n][j] - mx);
#pragma unroll
      for (int s = 1; s <= 8; s <<= 1) sm += __shfl_xor(sm, s, 64);
      if ((lane & 15) == 0) {
        int r = rbase + m * 16 + ((lane >> 4) << 2) + j;
        rowpart[(((size_t)mat * BROWS + r) << 5) + cb * 2 + wn] = make_float2(mx, sm);
      }
    }

#pragma unroll
  for (int n = 0; n < 4; ++n) {
    float mx = -3e38f;
#pragma unroll
    for (int m = 0; m < 4; ++m)
#pragma unroll
      for (int j = 0; j < 4; ++j) mx = fmaxf(mx, acc[m][n][j]);
#pragma unroll
    for (int s = 16; s <= 32; s <<= 1) mx = fmaxf(mx, __shfl_xor(mx, s, 64));
    float sm = 0.f;
#pragma unroll
    for (int m = 0; m < 4; ++m)
#pragma unroll
      for (int j = 0; j < 4; ++j) sm += __expf(acc[m][n][j] - mx);
#pragma unroll
    for (int s = 16; s <= 32; s <<= 1) sm += __shfl_xor(sm, s, 64);
    if (lane < 16) {
      int c = cbase + n * 16 + lane;
      colpart[(((size_t)mat * BROWS + c) << 5) + rb * 2 + wm] = make_float2(mx, sm);
    }
  }

#pragma unroll
  for (int m = 0; m < 4; ++m)
#pragma unroll
    for (int n = 0; n < 4; ++n)
#pragma unroll
      for (int j = 0; j < 4; ++j) {
        int rg = rbase + m * 16 + ((lane >> 4) << 2) + j;
        int cg = cbase + n * 16 + (lane & 15);
        if (rg == cg) diag[mat * BROWS + rg] = acc[m][n][j];
      }

  // FIFO copy slice: block id 0..511, 31 float4 per thread (exact cover)
  {
    int cbid = cb + rb * 16 + mat * 256;
    const float4* src = reinterpret_cast<const float4*>(cq);
    float4* dst = reinterpret_cast<float4*>(copydst);
    size_t base = (size_t)cbid * 7936 + (size_t)tid;
#pragma unroll 4
    for (int k = 0; k < 31; ++k) dst[base + (size_t)k * 256] = src[base + (size_t)k * 256];
  }
}

// ---- 8a. per-64-row loss partials (64 blocks) ----
__global__ void loss_part(const float2* __restrict__ rowpart, const float2* __restrict__ colpart,
                          const float* __restrict__ diag, float* __restrict__ lpart) {
  __shared__ float red[256];
  int tid = threadIdx.x;
  int r = blockIdx.x * 64 + (tid >> 2), q = tid & 3;
  const float2* rp = rowpart + ((size_t)r << 5) + q * 8;
  float2 e[8];
#pragma unroll
  for (int i = 0; i < 8; ++i) e[i] = rp[i];
  float mx = e[0].x;
#pragma unroll
  for (int i = 1; i < 8; ++i) mx = fmaxf(mx, e[i].x);
  mx = fmaxf(mx, __shfl_xor(mx, 1, 64));
  mx = fmaxf(mx, __shfl_xor(mx, 2, 64));
  float s = 0.f;
#pragma unroll
  for (int i = 0; i < 8; ++i) s += e[i].y * __expf(e[i].x - mx);
  s += __shfl_xor(s, 1, 64);
  s += __shfl_xor(s, 2, 64);
  float rlse = mx + __logf(s);

  const float2* cp = colpart + ((size_t)r << 5) + q * 8;
#pragma unroll
  for (int i = 0; i < 8; ++i) e[i] = cp[i];
  float mx2 = e[0].x;
#pragma unroll
  for (int i = 1; i < 8; ++i) mx2 = fmaxf(mx2, e[i].x);
  mx2 = fmaxf(mx2, __shfl_xor(mx2, 1, 64));
  mx2 = fmaxf(mx2, __shfl_xor(mx2, 2, 64));
  float s2 = 0.f;
#pragma unroll
  for (int i = 0; i < 8; ++i) s2 += e[i].y * __expf(e[i].x - mx2);
  s2 += __shfl_xor(s2, 1, 64);
  s2 += __shfl_xor(s2, 2, 64);
  float clse = mx2 + __logf(s2);

  red[tid] = (q == 0) ? (rlse + clse - 2.f * diag[r]) : 0.f;
  __syncthreads();
  for (int st = 128; st > 0; st >>= 1) {
    if (tid < st) red[tid] += red[tid + st];
    __syncthreads();
  }
  if (tid == 0) lpart[blockIdx.x] = red[0];
}

// ---- 8b. final scalar ----
__global__ void loss_final(const float* __restrict__ lpart, float* __restrict__ out) {
  int lane = threadIdx.x;
  float v = lpart[lane];
#pragma unroll
  for (int m = 1; m <= 32; m <<= 1) v += __shfl_xor(v, m, 64);
  if (lane == 0) out[0] = v * (1.f / 8192.f);
}

extern "C" void kernel_launch(void* const* d_in, const int* in_sizes, int n_in,
                              void* d_out, int out_size, void* d_ws, size_t ws_size,
                              hipStream_t stream) {
  const float* h1 = (const float*)d_in[0];
  const float* h2 = (const float*)d_in[1];
  const float* W1 = (const float*)d_in[2];
  const float* b1 = (const float*)d_in[3];
  const float* W2 = (const float*)d_in[4];
  const float* b2 = (const float*)d_in[5];
  const float* fq = (const float*)d_in[6];
  float* out = (float*)d_out;

  char* ws = (char*)d_ws;
  u16* Wt        = (u16*)(ws);                        // [2][256][256] bf16   (256 KB)
  u16* Ybf       = (u16*)(ws + 262144);               // [4096][256] bf16     (2 MB)
  float* Z       = (float*)(ws + 2359296);            // [4096][256] f32      (4 MB)
  u16* ZNb       = (u16*)(ws + 6553600);              // [4096][256] bf16     (2 MB)
  unsigned* nkey = (unsigned*)(ws + 8650752);         // [4096][1024] u32     (16 MB)
  u16* NNb       = (u16*)(ws + 25444352);             // [4096][256] bf16     (2 MB)
  float2* rowp   = (float2*)(ws + 27541504);          // [2][2048][32]        (1 MB)
  float2* colp   = (float2*)(ws + 28590080);          // [2][2048][32]        (1 MB)
  float* diag    = (float*)(ws + 29638656);           // [2][2048]
  float* lpart   = (float*)(ws + 29655040);           // [64]

  wt_convert<<<dim3(2, 8), dim3(256), 0, stream>>>(W1, W2, Wt);
  proj_kernel<true, true><<<dim3(2, 64), dim3(256), 0, stream>>>(
      h1, h2, (const u16*)nullptr, Wt, b1, Ybf, (float*)nullptr);
  proj_kernel<false, false><<<dim3(2, 64), dim3(256), 0, stream>>>(
      (const float*)nullptr, (const float*)nullptr, Ybf, Wt + 65536, b2, (u16*)nullptr, Z);
  normalize_k<<<dim3(1024), dim3(256), 0, stream>>>(Z, ZNb, out + 1);
  nn_gemm<<<dim3(256, 2), dim3(256), 0, stream>>>(fq, ZNb, nkey);
  nn_finish<<<dim3(1024), dim3(256), 0, stream>>>(nkey, fq, NNb);
  ce_gemm<<<dim3(16, 16, 2), dim3(256), 0, stream>>>(NNb, ZNb, rowp, colp, diag,
                                                     fq, out + 1 + (size_t)BROWS * D);
  loss_part<<<dim3(64), dim3(256), 0, stream>>>(rowp, colp, diag, lpart);
  loss_final<<<dim3(1), dim3(64), 0, stream>>>(lpart, out);
}